// Round 4
// baseline (790.757 us; speedup 1.0000x reference)
//
#include <hip/hip_runtime.h>
#include <hip/hip_fp16.h>

#define BP_EPS 1e-12f
#define BP_K 8
#define LOG_C 2.0f      // centering offset: stored = log(m) + LOG_C
#define BSH 6           // nodes per bucket = 64
#define BNODES 64
#define NB1 512         // edge chunks (blocks) for hist + scatter

typedef __attribute__((ext_vector_type(8))) _Float16 half8;

// ===========================================================================
// Build: group directed edges by destination node WITHOUT global atomics.
// Payload encoding: at node u (=src) the incoming direction is (v->u) =
// (e<<1)|1 (msgs row e+Eu); at node v it's (u->v) = (e<<1)|0 (msgs row e).
// k_csr emits pos[payload] = slot and nod[slot] = node. rev comes free from
// pos pairs: the reverse slot of pos[2e] is pos[2e+1] and vice versa.
// Messages LIVE in CSR slot order: per-iteration reads are fully sequential;
// the update scatter-writes to rev[s] (a permutation, no atomics).
// ===========================================================================

__global__ void k_hist(const int* __restrict__ src, const int* __restrict__ dst,
                       int* __restrict__ G, int Eu, int nbuck) {
    extern __shared__ int h[];
    for (int i = threadIdx.x; i < nbuck; i += blockDim.x) h[i] = 0;
    __syncthreads();
    int per = (Eu + NB1 - 1) / NB1;
    int s0 = blockIdx.x * per;
    int s1 = min(s0 + per, Eu);
    for (int e = s0 + threadIdx.x; e < s1; e += blockDim.x) {
        atomicAdd(&h[src[e] >> BSH], 1);
        atomicAdd(&h[dst[e] >> BSH], 1);
    }
    __syncthreads();
    for (int b = threadIdx.x; b < nbuck; b += blockDim.x)
        G[blockIdx.x * nbuck + b] = h[b];
}

__global__ void k_scanG(const int* __restrict__ G, int* __restrict__ Gpre,
                        int* __restrict__ total, int nbuck) {
    __shared__ int buf[NB1];
    int b = blockIdx.x;
    int t = threadIdx.x;
    int v = G[t * nbuck + b];
    buf[t] = v;
    __syncthreads();
    for (int off = 1; off < NB1; off <<= 1) {
        int x = (t >= off) ? buf[t - off] : 0;
        __syncthreads();
        buf[t] += x;
        __syncthreads();
    }
    Gpre[b * NB1 + t] = buf[t] - v;
    if (t == NB1 - 1) total[b] = buf[t];
}

__global__ void k_scanT(const int* __restrict__ total, int* __restrict__ base,
                        int nbuck, int* __restrict__ row_n, int E) {
    __shared__ int buf[1024];
    int t = threadIdx.x;
    int carry = 0;
    for (int s = 0; s < nbuck; s += 1024) {
        int i = s + t;
        int v = (i < nbuck) ? total[i] : 0;
        buf[t] = v;
        __syncthreads();
        for (int off = 1; off < 1024; off <<= 1) {
            int x = (t >= off) ? buf[t - off] : 0;
            __syncthreads();
            buf[t] += x;
            __syncthreads();
        }
        if (i < nbuck) base[i] = carry + buf[t] - v;
        carry += buf[1023];
        __syncthreads();
    }
    if (t == 0) { base[nbuck] = carry; *row_n = E; }
}

__global__ void k_scatter(const int* __restrict__ src, const int* __restrict__ dst,
                          const int* __restrict__ Gpre, const int* __restrict__ base,
                          int2* __restrict__ items, int Eu, int nbuck) {
    extern __shared__ int cur[];
    int blk = blockIdx.x;
    for (int i = threadIdx.x; i < nbuck; i += blockDim.x)
        cur[i] = base[i] + Gpre[i * NB1 + blk];
    __syncthreads();
    int per = (Eu + NB1 - 1) / NB1;
    int s0 = blk * per;
    int s1 = min(s0 + per, Eu);
    for (int e = s0 + threadIdx.x; e < s1; e += blockDim.x) {
        int u = src[e], v = dst[e];
        int pu = atomicAdd(&cur[u >> BSH], 1);
        items[pu] = make_int2(u, (e << 1) | 1);
        int pv = atomicAdd(&cur[v >> BSH], 1);
        items[pv] = make_int2(v, (e << 1) | 0);
    }
}

// bucket -> per-node CSR; emit pos[payload] = slot and nod[slot] = node.
__global__ void k_csr(const int2* __restrict__ items, const int* __restrict__ base,
                      int* __restrict__ row, int* __restrict__ pos,
                      int* __restrict__ nod, int n) {
    __shared__ int deg[BNODES];
    __shared__ int cur[BNODES];
    int b = blockIdx.x;
    int lo = base[b], hi = base[b + 1];
    int node0 = b << BSH;
    if (threadIdx.x < BNODES) deg[threadIdx.x] = 0;
    __syncthreads();
    for (int i = lo + threadIdx.x; i < hi; i += blockDim.x)
        atomicAdd(&deg[items[i].x - node0], 1);
    __syncthreads();
    if (threadIdx.x == 0) {
        int acc = 0;
        for (int t = 0; t < BNODES; ++t) { int d = deg[t]; deg[t] = acc; acc += d; }
    }
    __syncthreads();
    if (threadIdx.x < BNODES) {
        int node = node0 + threadIdx.x;
        if (node < n) row[node] = lo + deg[threadIdx.x];
        cur[threadIdx.x] = deg[threadIdx.x];
    }
    __syncthreads();
    for (int i = lo + threadIdx.x; i < hi; i += blockDim.x) {
        int2 x = items[i];
        int p = atomicAdd(&cur[x.x - node0], 1);
        int slot = lo + p;
        pos[x.y] = slot;
        nod[slot] = x.x;
    }
}

// rev from pos pairs: slots pos[2e] and pos[2e+1] are mutual reverses.
__global__ void k_rev(const int* __restrict__ pos, int* __restrict__ rev, int Eu) {
    int e = blockIdx.x * blockDim.x + threadIdx.x;
    if (e < Eu) {
        int2 p = ((const int2*)pos)[e];
        rev[p.x] = p.y;
        rev[p.y] = p.x;
    }
}

// LP[i][k] = log(max(prior, eps)) -- folded into the aggregate S once.
__global__ void k_lp(const float* __restrict__ prior, float* __restrict__ LP, int n8) {
    int i = blockIdx.x * blockDim.x + threadIdx.x;
    if (i < n8) LP[i] = __logf(fmaxf(prior[i], BP_EPS));
}

// Permute fp32 edge-order input msgs -> fp16 centered-log in slot order.
// Sequential reads of both directions; two 16B scatter writes per edge.
__global__ void __launch_bounds__(256) k_perm(
        const float* __restrict__ msgs, const int* __restrict__ pos,
        _Float16* __restrict__ W, int Eu) {
    int e = blockIdx.x * blockDim.x + threadIdx.x;
    if (e >= Eu) return;
    int2 p = ((const int2*)pos)[e];   // p.x: slot of row e; p.y: slot of row e+Eu
    const float4* a4 = (const float4*)(msgs + (size_t)e * BP_K);
    const float4* b4 = (const float4*)(msgs + ((size_t)e + (size_t)Eu) * BP_K);
    float4 xa = a4[0], xb = a4[1], ya = b4[0], yb = b4[1];
    float v0[BP_K] = {xa.x, xa.y, xa.z, xa.w, xb.x, xb.y, xb.z, xb.w};
    float v1[BP_K] = {ya.x, ya.y, ya.z, ya.w, yb.x, yb.y, yb.z, yb.w};
    half8 o0, o1;
#pragma unroll
    for (int k = 0; k < BP_K; ++k) {
        o0[k] = (_Float16)(__logf(fmaxf(v0[k], BP_EPS)) + LOG_C);
        o1[k] = (_Float16)(__logf(fmaxf(v1[k], BP_EPS)) + LOG_C);
    }
    *(half8*)(W + (size_t)p.x * BP_K) = o0;
    *(half8*)(W + (size_t)p.y * BP_K) = o1;
}

// ===========================================================================
// Per-iteration kernels, shaped to their work:
// k_reduce (node-shaped): S[i] = sum_row(log msgs) + log prior. Sequential.
// k_emit (slot-shaped): per slot s=(j->i): m_new(i->j) =
//   norm(max(exp(S[i]-lm[s]),eps) @ psi); 16B scatter to Wn[rev[s]].
// ===========================================================================

__global__ void __launch_bounds__(256) k_reduce(
        const _Float16* __restrict__ Wc, const int* __restrict__ row,
        const float* __restrict__ LP, float* __restrict__ S, int n) {
    int half = threadIdx.x >> 5;
    int sl = threadIdx.x & 31;
    int i = blockIdx.x * 8 + half;
    if (i >= n) return;

    int r0 = row[i];
    int r1 = row[i + 1];

    float s[BP_K];
#pragma unroll
    for (int k = 0; k < BP_K; ++k) s[k] = 0.0f;

    for (int j = r0 + sl; j < r1; j += 32) {
        half8 h = *(const half8*)(Wc + (size_t)j * BP_K);
#pragma unroll
        for (int k = 0; k < BP_K; ++k) s[k] += (float)h[k] - LOG_C;
    }

#pragma unroll
    for (int off = 16; off >= 1; off >>= 1) {
#pragma unroll
        for (int k = 0; k < BP_K; ++k) s[k] += __shfl_xor(s[k], off);
    }

    if (sl == 0) {
        const float4* lp4 = (const float4*)(LP + (size_t)i * BP_K);
        float4 la = lp4[0], lb = lp4[1];
        float4* o4 = (float4*)(S + (size_t)i * BP_K);
        o4[0] = {s[0] + la.x, s[1] + la.y, s[2] + la.z, s[3] + la.w};
        o4[1] = {s[4] + lb.x, s[5] + lb.y, s[6] + lb.z, s[7] + lb.w};
    }
}

__global__ void __launch_bounds__(256) k_emit(
        const _Float16* __restrict__ Wc, const float* __restrict__ S,
        const int* __restrict__ nod, const int* __restrict__ rev,
        const float* __restrict__ potential, _Float16* __restrict__ Wn, int E) {
    __shared__ float psi[BP_K * BP_K];
    if (threadIdx.x < BP_K * BP_K) psi[threadIdx.x] = expf(potential[threadIdx.x]);
    __syncthreads();

    int s = blockIdx.x * blockDim.x + threadIdx.x;
    if (s >= E) return;

    half8 h = *(const half8*)(Wc + (size_t)s * BP_K);
    int i = nod[s];
    int rv = rev[s];

    const float4* s4 = (const float4*)(S + (size_t)i * BP_K);
    float4 sa = s4[0], sb = s4[1];
    float sv[BP_K] = {sa.x, sa.y, sa.z, sa.w, sb.x, sb.y, sb.z, sb.w};

    float bb[BP_K];
#pragma unroll
    for (int k = 0; k < BP_K; ++k) {
        float lm = (float)h[k] - LOG_C;
        bb[k] = fmaxf(__expf(sv[k] - lm), BP_EPS);
    }

    float mn[BP_K];
    float sum = 0.0f;
#pragma unroll
    for (int jj = 0; jj < BP_K; ++jj) {
        float acc = 0.0f;
#pragma unroll
        for (int k = 0; k < BP_K; ++k) acc += bb[k] * psi[k * BP_K + jj];
        mn[jj] = acc;
        sum += acc;
    }
    float inv = 1.0f / fmaxf(sum, BP_EPS);

    half8 o;
#pragma unroll
    for (int jj = 0; jj < BP_K; ++jj)
        o[jj] = (_Float16)(__logf(fmaxf(mn[jj] * inv, BP_EPS)) + LOG_C);

    *(half8*)(Wn + (size_t)rv * BP_K) = o;
}

// Final beliefs: sequential row read, normalize with prior (via LP).
__global__ void __launch_bounds__(256) k_belief(
        const _Float16* __restrict__ Wc, const int* __restrict__ row,
        const float* __restrict__ LP, float* __restrict__ out, int n) {
    int half = threadIdx.x >> 5;
    int sl = threadIdx.x & 31;
    int i = blockIdx.x * 8 + half;
    if (i >= n) return;

    int r0 = row[i];
    int r1 = row[i + 1];

    float s[BP_K];
#pragma unroll
    for (int k = 0; k < BP_K; ++k) s[k] = 0.0f;

    for (int j = r0 + sl; j < r1; j += 32) {
        half8 h = *(const half8*)(Wc + (size_t)j * BP_K);
#pragma unroll
        for (int k = 0; k < BP_K; ++k) s[k] += (float)h[k] - LOG_C;
    }

#pragma unroll
    for (int off = 16; off >= 1; off >>= 1) {
#pragma unroll
        for (int k = 0; k < BP_K; ++k) s[k] += __shfl_xor(s[k], off);
    }

    if (sl == 0) {
        const float4* lp4 = (const float4*)(LP + (size_t)i * BP_K);
        float4 la = lp4[0], lb = lp4[1];
        float lp[BP_K] = {la.x, la.y, la.z, la.w, lb.x, lb.y, lb.z, lb.w};
        float b[BP_K];
        float sum = 0.0f;
#pragma unroll
        for (int k = 0; k < BP_K; ++k) {
            b[k] = fmaxf(__expf(s[k] + lp[k]), BP_EPS);
            sum += b[k];
        }
        float inv = 1.0f / fmaxf(sum, BP_EPS);
        float4* o4 = (float4*)(out + (size_t)i * BP_K);
        o4[0] = {b[0] * inv, b[1] * inv, b[2] * inv, b[3] * inv};
        o4[1] = {b[4] * inv, b[5] * inv, b[6] * inv, b[7] * inv};
    }
}

extern "C" void kernel_launch(void* const* d_in, const int* in_sizes, int n_in,
                              void* d_out, int out_size, void* d_ws, size_t ws_size,
                              hipStream_t stream) {
    const float* prior     = (const float*)d_in[0];
    const float* msgs      = (const float*)d_in[1];
    const float* potential = (const float*)d_in[2];
    const int*   src       = (const int*)d_in[3];
    const int*   dst       = (const int*)d_in[4];
    const int ITERS = 5;   // fixed by setup_inputs

    int n  = in_sizes[0] / BP_K;
    int E  = in_sizes[3];
    int Eu = E / 2;
    int nbuck = (n + BNODES - 1) >> BSH;

    char* w = (char*)d_ws;
    _Float16* W1 = (_Float16*)w;   w += (size_t)Eu * 16 * sizeof(_Float16);
    _Float16* W2 = (_Float16*)w;   w += (size_t)Eu * 16 * sizeof(_Float16);
    float* LP    = (float*)w;      w += (size_t)n * BP_K * sizeof(float);
    int*   G     = (int*)w;        w += (size_t)NB1 * nbuck * sizeof(int);
    int*   Gpre  = (int*)w;        w += (size_t)NB1 * nbuck * sizeof(int);
    int*   total = (int*)w;        w += (size_t)nbuck * sizeof(int);
    int*   base  = (int*)w;        w += (size_t)(nbuck + 1) * sizeof(int);
    int*   row   = (int*)w;        w += (size_t)(n + 1) * sizeof(int);
    int*   rev   = (int*)w;        w += (size_t)E * sizeof(int);
    int*   nod   = (int*)w;        w += (size_t)E * sizeof(int);
    float* S     = (float*)w;      w += (size_t)n * BP_K * sizeof(float);
    // items + pos alias W2: both dead before W2's first write (emit #1).
    int2*  items = (int2*)W2;
    int*   pos   = (int*)((char*)W2 + (size_t)E * sizeof(int2));

    float* out = (float*)d_out;

    dim3 blk(256);
    dim3 grdEu((Eu + 255) / 256);
    dim3 grdE((E + 255) / 256);
    dim3 grdNode((n + 7) / 8);     // 8 half-waves/block, half-wave per node
    size_t lds_hist = (size_t)nbuck * sizeof(int);

    // --- build: bucket-grouping CSR + pos/nod/rev maps, no global atomics ---
    k_hist   <<<NB1, blk, lds_hist, stream>>>(src, dst, G, Eu, nbuck);
    k_scanG  <<<nbuck, NB1, 0, stream>>>(G, Gpre, total, nbuck);
    k_scanT  <<<1, 1024, 0, stream>>>(total, base, nbuck, row + n, E);
    k_scatter<<<NB1, blk, lds_hist, stream>>>(src, dst, Gpre, base, items, Eu, nbuck);
    k_csr    <<<nbuck, blk, 0, stream>>>(items, base, row, pos, nod, n);
    k_rev    <<<grdEu, blk, 0, stream>>>(pos, rev, Eu);
    k_lp     <<<(n * BP_K + 255) / 256, blk, 0, stream>>>(prior, LP, n * BP_K);

    // --- one-time permute: edge-order fp32 msgs -> slot-order fp16 log ---
    k_perm<<<grdEu, blk, 0, stream>>>(msgs, pos, W1, Eu);

    // --- 5 uniform iterations: node-shaped reduce + slot-shaped emit ---
    _Float16* cur = W1;
    _Float16* nxt = W2;
    for (int it = 0; it < ITERS; ++it) {
        k_reduce<<<grdNode, blk, 0, stream>>>(cur, row, LP, S, n);
        k_emit  <<<grdE, blk, 0, stream>>>(cur, S, nod, rev, potential, nxt, E);
        _Float16* tmp = cur; cur = nxt; nxt = tmp;
    }

    // --- final beliefs: sequential read of W ---
    k_belief<<<grdNode, blk, 0, stream>>>(cur, row, LP, out, n);
}